// Round 1
// baseline (65.447 us; speedup 1.0000x reference)
//
#include <hip/hip_runtime.h>
#include <hip/hip_bf16.h>
#include <math.h>

// Fixed-size problem: x(12), K(4x4), b(4), G(4x4), adj(4x4) -> out(12), all fp32.
// Single-wave kernel, lane 0 computes everything serially in registers.
// The only iterative piece is the dominant eigenvalue of M = G*G^T via power
// iteration (Perron-Frobenius: M is entrywise positive, so the all-ones start
// vector converges geometrically; 32 iters + Rayleigh quotient is exact to
// fp32 precision here).

__global__ void kuramoto_kernel(const float* __restrict__ x,
                                const float* __restrict__ K,
                                const float* __restrict__ b,
                                const float* __restrict__ G,
                                const float* __restrict__ adj,
                                float* __restrict__ out) {
    if (threadIdx.x != 0) return;

    float a[4], v[4], xi[4];
    #pragma unroll
    for (int i = 0; i < 4; ++i) {
        a[i]  = x[i];
        v[i]  = x[4 + i];
        xi[i] = x[8 + i];
    }

    // th = tanh(K @ xi + b)
    float th[4];
    #pragma unroll
    for (int i = 0; i < 4; ++i) {
        float s = b[i];
        #pragma unroll
        for (int j = 0; j < 4; ++j) s += K[i * 4 + j] * xi[j];
        th[i] = tanhf(s);
    }

    // dH = K^T @ th
    float dH[4];
    #pragma unroll
    for (int j = 0; j < 4; ++j) {
        float s = 0.0f;
        #pragma unroll
        for (int i = 0; i < 4; ++i) s += K[i * 4 + j] * th[i];
        dH[j] = s;
    }

    // interactions[j] = sum_i adj[i][j] * cos(a[j]-a[i]) * (v[j]-v[i])
    float inter[4];
    #pragma unroll
    for (int j = 0; j < 4; ++j) {
        float s = 0.0f;
        #pragma unroll
        for (int i = 0; i < 4; ++i)
            s += adj[i * 4 + j] * cosf(a[j] - a[i]) * (v[j] - v[i]);
        inter[j] = s;
    }

    // u = -(adj .* G)^T @ dH  ->  u[j] = -sum_i adj[i][j]*G[i][j]*dH[i]
    float u[4];
    #pragma unroll
    for (int j = 0; j < 4; ++j) {
        float s = 0.0f;
        #pragma unroll
        for (int i = 0; i < 4; ++i) s += adj[i * 4 + j] * G[i * 4 + j] * dH[i];
        u[j] = -s;
    }

    // M = G @ G^T (symmetric positive)
    float M[16];
    #pragma unroll
    for (int i = 0; i < 4; ++i) {
        #pragma unroll
        for (int j = 0; j < 4; ++j) {
            float s = 0.0f;
            #pragma unroll
            for (int k = 0; k < 4; ++k) s += G[i * 4 + k] * G[j * 4 + k];
            M[i * 4 + j] = s;
        }
    }

    // Power iteration for the dominant eigenvalue of M.
    float pv[4] = {1.0f, 1.0f, 1.0f, 1.0f};
    for (int it = 0; it < 32; ++it) {
        float w[4];
        #pragma unroll
        for (int i = 0; i < 4; ++i) {
            float s = 0.0f;
            #pragma unroll
            for (int j = 0; j < 4; ++j) s += M[i * 4 + j] * pv[j];
            w[i] = s;
        }
        float n2 = w[0]*w[0] + w[1]*w[1] + w[2]*w[2] + w[3]*w[3];
        float inv = rsqrtf(n2);
        #pragma unroll
        for (int i = 0; i < 4; ++i) pv[i] = w[i] * inv;
    }
    // Rayleigh quotient lam = pv^T M pv (pv is unit norm)
    float lam = 0.0f;
    #pragma unroll
    for (int i = 0; i < 4; ++i) {
        float s = 0.0f;
        #pragma unroll
        for (int j = 0; j < 4; ++j) s += M[i * 4 + j] * pv[j];
        lam += pv[i] * s;
    }
    float gamma = 0.1f * lam;

    // J @ dH with J = [[0,-1,0,0],[1,0,0,0],[0,0,0,-1],[0,0,1,0]]
    float JdH[4] = { -dH[1], dH[0], -dH[3], dH[2] };

    // dxi_dt = (J - gamma*I) @ dH + (adj .* G) @ x2
    float dxi[4];
    #pragma unroll
    for (int i = 0; i < 4; ++i) {
        float s = JdH[i] - gamma * dH[i];
        #pragma unroll
        for (int j = 0; j < 4; ++j) s += adj[i * 4 + j] * G[i * 4 + j] * v[j];
        dxi[i] = s;
    }

    // out = concat(x2, 1.25*u*inter, dxi)
    #pragma unroll
    for (int i = 0; i < 4; ++i) {
        out[i]     = v[i];
        out[4 + i] = 1.25f * u[i] * inter[i];
        out[8 + i] = dxi[i];
    }
}

extern "C" void kernel_launch(void* const* d_in, const int* in_sizes, int n_in,
                              void* d_out, int out_size, void* d_ws, size_t ws_size,
                              hipStream_t stream) {
    // inputs: 0=t(1), 1=x(12), 2=K(16), 3=b(4), 4=G(16), 5=adj(16) — all fp32
    const float* x   = (const float*)d_in[1];
    const float* K   = (const float*)d_in[2];
    const float* b   = (const float*)d_in[3];
    const float* G   = (const float*)d_in[4];
    const float* adj = (const float*)d_in[5];
    float* out = (float*)d_out;

    kuramoto_kernel<<<dim3(1), dim3(64), 0, stream>>>(x, K, b, G, adj, out);
}

// Round 2
// 64.769 us; speedup vs baseline: 1.0105x; 1.0105x over previous
//
#include <hip/hip_runtime.h>
#include <hip/hip_bf16.h>
#include <math.h>

// Fixed-size problem: x(12), K(4x4), b(4), G(4x4), adj(4x4) -> out(12), all fp32.
// Single-wave kernel, lane 0 computes everything serially in registers.
// Dominant eigenvalue of M = G*G^T via power iteration (Perron-Frobenius:
// M entrywise positive -> all-ones start converges geometrically; ratio^2 per
// iter, 12 iters is orders of magnitude inside the 4.8e-2 threshold).
// Final Rayleigh quotient folded into the last iteration (lam = pv . M pv).

__global__ void kuramoto_kernel(const float* __restrict__ x,
                                const float* __restrict__ K,
                                const float* __restrict__ b,
                                const float* __restrict__ G,
                                const float* __restrict__ adj,
                                float* __restrict__ out) {
    if (threadIdx.x != 0) return;

    // Issue all global loads up front so their latency overlaps.
    float a[4], v[4], xi[4], Kr[16], br[4], Gr[16], adjr[16];
    #pragma unroll
    for (int i = 0; i < 4; ++i) {
        a[i]  = x[i];
        v[i]  = x[4 + i];
        xi[i] = x[8 + i];
        br[i] = b[i];
    }
    #pragma unroll
    for (int i = 0; i < 16; ++i) {
        Kr[i]   = K[i];
        Gr[i]   = G[i];
        adjr[i] = adj[i];
    }

    // th = tanh(K @ xi + b)
    float th[4];
    #pragma unroll
    for (int i = 0; i < 4; ++i) {
        float s = br[i];
        #pragma unroll
        for (int j = 0; j < 4; ++j) s += Kr[i * 4 + j] * xi[j];
        th[i] = tanhf(s);
    }

    // dH = K^T @ th
    float dH[4];
    #pragma unroll
    for (int j = 0; j < 4; ++j) {
        float s = 0.0f;
        #pragma unroll
        for (int i = 0; i < 4; ++i) s += Kr[i * 4 + j] * th[i];
        dH[j] = s;
    }

    // interactions[j] = sum_i adj[i][j] * cos(a[j]-a[i]) * (v[j]-v[i])
    float inter[4];
    #pragma unroll
    for (int j = 0; j < 4; ++j) {
        float s = 0.0f;
        #pragma unroll
        for (int i = 0; i < 4; ++i)
            s += adjr[i * 4 + j] * cosf(a[j] - a[i]) * (v[j] - v[i]);
        inter[j] = s;
    }

    // u = -(adj .* G)^T @ dH  ->  u[j] = -sum_i adj[i][j]*G[i][j]*dH[i]
    float u[4];
    #pragma unroll
    for (int j = 0; j < 4; ++j) {
        float s = 0.0f;
        #pragma unroll
        for (int i = 0; i < 4; ++i) s += adjr[i * 4 + j] * Gr[i * 4 + j] * dH[i];
        u[j] = -s;
    }

    // M = G @ G^T (symmetric, entrywise positive)
    float M[16];
    #pragma unroll
    for (int i = 0; i < 4; ++i) {
        #pragma unroll
        for (int j = 0; j < 4; ++j) {
            float s = 0.0f;
            #pragma unroll
            for (int k = 0; k < 4; ++k) s += Gr[i * 4 + k] * Gr[j * 4 + k];
            M[i * 4 + j] = s;
        }
    }

    // Power iteration; last pass yields lam = pv^T M pv with pv unit-norm.
    float pv[4] = {1.0f, 1.0f, 1.0f, 1.0f};
    float lam = 0.0f;
    #pragma unroll
    for (int it = 0; it < 12; ++it) {
        float w[4];
        #pragma unroll
        for (int i = 0; i < 4; ++i) {
            float s = 0.0f;
            #pragma unroll
            for (int j = 0; j < 4; ++j) s += M[i * 4 + j] * pv[j];
            w[i] = s;
        }
        if (it == 11) {
            // pv is unit-norm here; Rayleigh quotient.
            lam = pv[0]*w[0] + pv[1]*w[1] + pv[2]*w[2] + pv[3]*w[3];
        } else {
            float n2 = w[0]*w[0] + w[1]*w[1] + w[2]*w[2] + w[3]*w[3];
            float inv = rsqrtf(n2);
            #pragma unroll
            for (int i = 0; i < 4; ++i) pv[i] = w[i] * inv;
        }
    }
    float gamma = 0.1f * lam;

    // J @ dH with J = [[0,-1,0,0],[1,0,0,0],[0,0,0,-1],[0,0,1,0]]
    float JdH[4] = { -dH[1], dH[0], -dH[3], dH[2] };

    // dxi_dt = (J - gamma*I) @ dH + (adj .* G) @ x2
    float dxi[4];
    #pragma unroll
    for (int i = 0; i < 4; ++i) {
        float s = JdH[i] - gamma * dH[i];
        #pragma unroll
        for (int j = 0; j < 4; ++j) s += adjr[i * 4 + j] * Gr[i * 4 + j] * v[j];
        dxi[i] = s;
    }

    // out = concat(x2, 1.25*u*inter, dxi)
    #pragma unroll
    for (int i = 0; i < 4; ++i) {
        out[i]     = v[i];
        out[4 + i] = 1.25f * u[i] * inter[i];
        out[8 + i] = dxi[i];
    }
}

extern "C" void kernel_launch(void* const* d_in, const int* in_sizes, int n_in,
                              void* d_out, int out_size, void* d_ws, size_t ws_size,
                              hipStream_t stream) {
    // inputs: 0=t(1), 1=x(12), 2=K(16), 3=b(4), 4=G(16), 5=adj(16) — all fp32
    const float* x   = (const float*)d_in[1];
    const float* K   = (const float*)d_in[2];
    const float* b   = (const float*)d_in[3];
    const float* G   = (const float*)d_in[4];
    const float* adj = (const float*)d_in[5];
    float* out = (float*)d_out;

    kuramoto_kernel<<<dim3(1), dim3(64), 0, stream>>>(x, K, b, G, adj, out);
}